// Round 8
// baseline (300.767 us; speedup 1.0000x reference)
//
#include <hip/hip_runtime.h>
#include <cstdint>
#include <cstddef>

#define NB   4
#define NLQ  2048
#define NLK  2048
#define NDIM 1024
#define NH   16
#define ND   64
#define NAD  1024

typedef __attribute__((ext_vector_type(8))) short bf16x8;
typedef __attribute__((ext_vector_type(4))) short sh4;
typedef __attribute__((ext_vector_type(4))) float f32x4;
typedef __attribute__((ext_vector_type(4))) int   i32x4;

static __device__ __forceinline__ short f2bf(float f) {
    unsigned u = __builtin_bit_cast(unsigned, f);
    u += 0x7fffu + ((u >> 16) & 1u);     // round-to-nearest-even
    return (short)(u >> 16);
}

// async global->LDS, 16B per lane; LDS dest lane-contiguous (global side may be swizzled)
#define GLL16(GP, LP) __builtin_amdgcn_global_load_lds( \
    (const __attribute__((address_space(1))) void*)(GP), \
    (__attribute__((address_space(3))) void*)(LP), 16, 0, 0)

// LDS-producer barrier WITHOUT the vmcnt drain of __syncthreads():
// drains only lgkmcnt (ds_writes visible), leaves global prefetch in flight.
#define SYNC_LDS do { \
    __builtin_amdgcn_sched_barrier(0); \
    asm volatile("s_waitcnt lgkmcnt(0)" ::: "memory"); \
    __builtin_amdgcn_s_barrier(); \
    asm volatile("" ::: "memory"); \
    __builtin_amdgcn_sched_barrier(0); } while (0)

// ---------------- fp32 -> bf16, x and embeds in one launch ----------------
__global__ void cvt2(const float* __restrict__ x, const float* __restrict__ e,
                     short* __restrict__ xo, short* __restrict__ eo) {
    const float* in = blockIdx.y ? e : x;
    short* out = blockIdx.y ? eo : xo;
    int i = (blockIdx.x * blockDim.x + threadIdx.x) * 4;
    const float4 v = *(const float4*)(in + i);
    sh4 o;
    o.x = f2bf(v.x); o.y = f2bf(v.y); o.z = f2bf(v.z); o.w = f2bf(v.w);
    *(sh4*)(out + i) = o;
}

// ---------------- 4x W[1024][1024] fp32 -> Wt[n][k] bf16 in one launch ----------------
__global__ void wtrans4(const float* __restrict__ W0, const float* __restrict__ W1,
                        const float* __restrict__ W2, const float* __restrict__ W3,
                        short* __restrict__ T0, short* __restrict__ T1,
                        short* __restrict__ T2, short* __restrict__ T3) {
    __shared__ float t[32][33];
    const int z = blockIdx.z;
    const float* W = (z == 0) ? W0 : (z == 1) ? W1 : (z == 2) ? W2 : W3;
    short* Wt = (z == 0) ? T0 : (z == 1) ? T1 : (z == 2) ? T2 : T3;
    const int bx = blockIdx.x * 32;   // k block
    const int by = blockIdx.y * 32;   // n block
    const int tx = threadIdx.x & 31, ty = threadIdx.x >> 5;
    #pragma unroll
    for (int i = 0; i < 32; i += 8)
        t[ty + i][tx] = W[(size_t)(bx + ty + i) * 1024 + by + tx];
    __syncthreads();
    #pragma unroll
    for (int i = 0; i < 32; i += 8)
        Wt[(size_t)(by + ty + i) * 1024 + bx + tx] = f2bf(t[tx][ty + i]);
}

// XCD L2-tiling remap for a 64x8 (x,y) block plane (512 blocks, 512%8==0 ->
// bijective). Dispatch order round-robins XCDs by linear id; give XCD k an
// 8x8 (x',y') super-tile: 8 A-panels + 8 B-panels = 2+2 MB = fits 4 MB L2.
static __device__ __forceinline__ void xcd_tile_remap(int f, int& bx, int& by) {
    bx = ((f & 7) << 3) | ((f >> 3) & 7);   // x' = 8*xcd + slot%8
    by = f >> 6;                            // y' = slot/8
}

// =====================================================================
// BK=64 GEMM body: C[M,1024] = A[M,1024] @ Wt[1024,1024]^T.
// (128x128 tile, 4 waves, 2-barrier loop; 256x256 deep-pipeline port
// measured WORSE here — retained.)
// LDS rows are 64 shorts (128 B) -> XOR-swizzle 16B chunks applied on the
// GLOBAL address (global_load_lds needs lane-contiguous LDS dest); frag
// reads apply the matching XOR -> conflict-free b128.
// =====================================================================

// ---------------- fused Q/K/V projection GEMMs (one launch, grid.z selects) ----------------
__global__ __launch_bounds__(256) void gemm_qkv(const short* __restrict__ Xb,
                                                const short* __restrict__ Eb,
                                                const short* __restrict__ Wqt,
                                                const short* __restrict__ Wkt,
                                                const short* __restrict__ Wvt,
                                                const float* __restrict__ bq,
                                                const float* __restrict__ bk,
                                                const float* __restrict__ bv,
                                                short* __restrict__ Qb,
                                                short* __restrict__ Kf,
                                                short* __restrict__ Vtb)
{
    const int N = 1024, K = 1024;
    __shared__ __align__(16) short As[128 * 64];
    __shared__ __align__(16) short Bs[128 * 64];
    const int z = blockIdx.z;
    const short* A    = (z == 0) ? Xb : Eb;
    const short* Wt   = (z == 0) ? Wqt : (z == 1) ? Wkt : Wvt;
    const float* bias = (z == 0) ? bq : (z == 1) ? bk : bv;
    const float scale = (z == 0) ? 0.18033688011112042f : 1.0f;   // SCALE * LOG2E

    const int tid = threadIdx.x, wave = tid >> 6, lane = tid & 63;
    const int quad = lane >> 4, col = lane & 15;
    int bx, by;
    xcd_tile_remap(blockIdx.x + (blockIdx.y << 6), bx, by);
    const int m0 = bx * 128, n0 = by * 128;
    const int wm = wave >> 1, wn = wave & 1;

    const f32x4 zero = {0.f, 0.f, 0.f, 0.f};
    f32x4 acc[4][4];
    #pragma unroll
    for (int i = 0; i < 4; ++i)
        #pragma unroll
        for (int j = 0; j < 4; ++j)
            acc[i][j] = zero;

    for (int kt = 0; kt < K / 64; ++kt) {
        __syncthreads();
        #pragma unroll
        for (int i = 0; i < 4; ++i) {
            const int f = (i * 4 + wave) * 512 + lane * 8;   // lane-contiguous LDS offset
            const int row = f >> 6, ch = (f >> 3) & 7;
            const int gcol = kt * 64 + ((ch ^ (row & 7)) * 8);  // global-side swizzle
            GLL16(A  + (size_t)(m0 + row) * K + gcol, &As[f]);
            GLL16(Wt + (size_t)(n0 + row) * K + gcol, &Bs[f]);
        }
        __syncthreads();
        #pragma unroll
        for (int kk = 0; kk < 2; ++kk) {
            bf16x8 af[4], bfr[4];
            #pragma unroll
            for (int mt = 0; mt < 4; ++mt) {
                const int r = wm * 64 + mt * 16 + col;
                af[mt] = *(const bf16x8*)&As[r * 64 + (((kk * 4 + quad) ^ (r & 7)) * 8)];
            }
            #pragma unroll
            for (int nt = 0; nt < 4; ++nt) {
                const int r = wn * 64 + nt * 16 + col;
                bfr[nt] = *(const bf16x8*)&Bs[r * 64 + (((kk * 4 + quad) ^ (r & 7)) * 8)];
            }
            #pragma unroll
            for (int mt = 0; mt < 4; ++mt)
                #pragma unroll
                for (int nt = 0; nt < 4; ++nt)
                    acc[mt][nt] = __builtin_amdgcn_mfma_f32_16x16x32_bf16(af[mt], bfr[nt], acc[mt][nt], 0, 0, 0);
        }
    }

    if (z < 2) {
        short* outp = (z == 0) ? Qb : Kf;
        #pragma unroll
        for (int mt = 0; mt < 4; ++mt)
            #pragma unroll
            for (int nt = 0; nt < 4; ++nt) {
                const int n = n0 + wn * 64 + nt * 16 + col;
                const float bv_ = bias[n];
                #pragma unroll
                for (int r = 0; r < 4; ++r) {
                    const int m = m0 + wm * 64 + mt * 16 + quad * 4 + r;
                    outp[(size_t)m * N + n] = f2bf((acc[mt][nt][r] + bv_) * scale);
                }
            }
    } else {
        // V -> Vt[b,h,d,LK], packed 8B stores along s (r=0..3 contiguous in m)
        #pragma unroll
        for (int mt = 0; mt < 4; ++mt)
            #pragma unroll
            for (int nt = 0; nt < 4; ++nt) {
                const int n = n0 + wn * 64 + nt * 16 + col;
                const int hh = n >> 6, d = n & 63;
                const float bv_ = bias[n];
                const int mb = m0 + wm * 64 + mt * 16 + quad * 4;
                const int bb = mb >> 11, s = mb & 2047;
                sh4 o4;
                #pragma unroll
                for (int r = 0; r < 4; ++r)
                    o4[r] = f2bf(acc[mt][nt][r] + bv_);
                *(sh4*)&Vtb[((size_t)((bb * NH + hh) * 64 + d)) * NLK + s] = o4;
            }
    }
}

// ---------------- output projection GEMM (fp32 out), BK=64 ----------------
__global__ __launch_bounds__(256) void gemm_out(const short* __restrict__ A,
                                                const short* __restrict__ Wt,
                                                const float* __restrict__ bias,
                                                float* __restrict__ outp)
{
    const int N = 1024, K = 1024;
    __shared__ __align__(16) short As[128 * 64];
    __shared__ __align__(16) short Bs[128 * 64];
    const int tid = threadIdx.x, wave = tid >> 6, lane = tid & 63;
    const int quad = lane >> 4, col = lane & 15;
    int bx, by;
    xcd_tile_remap(blockIdx.x + (blockIdx.y << 6), bx, by);
    const int m0 = bx * 128, n0 = by * 128;
    const int wm = wave >> 1, wn = wave & 1;

    const f32x4 zero = {0.f, 0.f, 0.f, 0.f};
    f32x4 acc[4][4];
    #pragma unroll
    for (int i = 0; i < 4; ++i)
        #pragma unroll
        for (int j = 0; j < 4; ++j)
            acc[i][j] = zero;

    for (int kt = 0; kt < K / 64; ++kt) {
        __syncthreads();
        #pragma unroll
        for (int i = 0; i < 4; ++i) {
            const int f = (i * 4 + wave) * 512 + lane * 8;
            const int row = f >> 6, ch = (f >> 3) & 7;
            const int gcol = kt * 64 + ((ch ^ (row & 7)) * 8);
            GLL16(A  + (size_t)(m0 + row) * K + gcol, &As[f]);
            GLL16(Wt + (size_t)(n0 + row) * K + gcol, &Bs[f]);
        }
        __syncthreads();
        #pragma unroll
        for (int kk = 0; kk < 2; ++kk) {
            bf16x8 af[4], bfr[4];
            #pragma unroll
            for (int mt = 0; mt < 4; ++mt) {
                const int r = wm * 64 + mt * 16 + col;
                af[mt] = *(const bf16x8*)&As[r * 64 + (((kk * 4 + quad) ^ (r & 7)) * 8)];
            }
            #pragma unroll
            for (int nt = 0; nt < 4; ++nt) {
                const int r = wn * 64 + nt * 16 + col;
                bfr[nt] = *(const bf16x8*)&Bs[r * 64 + (((kk * 4 + quad) ^ (r & 7)) * 8)];
            }
            #pragma unroll
            for (int mt = 0; mt < 4; ++mt)
                #pragma unroll
                for (int nt = 0; nt < 4; ++nt)
                    acc[mt][nt] = __builtin_amdgcn_mfma_f32_16x16x32_bf16(af[mt], bfr[nt], acc[mt][nt], 0, 0, 0);
        }
    }

    #pragma unroll
    for (int mt = 0; mt < 4; ++mt)
        #pragma unroll
        for (int nt = 0; nt < 4; ++nt) {
            const int n = n0 + wn * 64 + nt * 16 + col;
            const float bv_ = bias[n];
            #pragma unroll
            for (int r = 0; r < 4; ++r) {
                const int m = m0 + wm * 64 + mt * 16 + quad * 4 + r;
                outp[(size_t)m * N + n] = acc[mt][nt][r] + bv_;
            }
        }
}

// ---------------- fused flash attention, v13 ----------------
// v12's interleaved-key Vs (bank conflicts = 0, PV = one b128/fragment)
// applied to v8's 8-wave occupancy structure. v8 (8 waves, mt=2, 4
// waves/SIMD) regressed BECAUSE its V-read path doubled bank conflicts
// (8.4M ~= 17% pure stall); with the conflict-free layout that failure
// mode is gone, and 4 waves/SIMD of phase diversity lets the CU scheduler
// overlap the MFMA and VALU pipes (which pipe-work arithmetic shows are
// each <50% of wall but serialized per-wave at 2 waves/SIMD). setprio
// (v8 predated it) now arbitrates across 4 waves instead of 2.
// Per-block traffic, MFMA/VALU totals unchanged vs v12.
__global__ __launch_bounds__(512, 4) void attn_fused13(const short* __restrict__ Q,
                                                       const short* __restrict__ Kb,
                                                       const short* __restrict__ Vt,
                                                       short* __restrict__ ctx)
{
    __shared__ __align__(16) short Ks[2][64 * 64];   // [buf][key][dim], 16B-chunk XOR swizzle
    __shared__ __align__(16) short Vs[2][64 * 64];   // [buf][d][key-interleaved], XOR swizzle
    const int tid = threadIdx.x, wave = tid >> 6, lane = tid & 63;
    const int quad = lane >> 4, col = lane & 15;

    // XCD-grouping decode (bijective on [0,512)): physical p -> xcd = p%8.
    // group g=(b,h) gets xcd = g%8; its 8 q-tile members are p = g%8 + 8*(qt*8 + g/8).
    const int p = blockIdx.x;
    const int g = ((p >> 3) & 7) * 8 + (p & 7);   // (b,h) group 0..63
    const int qt = p >> 6;                         // q-tile member 0..7
    const int h = g & 15, b = g >> 4;
    const int q0 = qt * 256 + wave * 32;           // 8 waves x 32 q-rows

    // Q B-fragments for the wave's 32 q-rows
    bf16x8 aq[2][2];
    #pragma unroll
    for (int mt = 0; mt < 2; ++mt) {
        const short* qp = Q + (size_t)(b * NLQ + q0 + mt * 16 + col) * NAD + h * 64 + quad * 8;
        aq[mt][0] = *(const bf16x8*)qp;
        aq[mt][1] = *(const bf16x8*)(qp + 32);
    }

    bf16x8 vones;
    #pragma unroll
    for (int j = 0; j < 8; ++j) vones[j] = (short)0x3F80;   // bf16 1.0

    const f32x4 zero = {0.f, 0.f, 0.f, 0.f};
    f32x4 O[4][2];          // [dblk][mtq], O^T C-layout
    f32x4 Ol[2];            // l accumulator (ones x P^T): all rows identical
    #pragma unroll
    for (int mt = 0; mt < 2; ++mt) {
        Ol[mt] = zero;
        #pragma unroll
        for (int db = 0; db < 4; ++db) O[db][mt] = zero;
    }

    const int srow = tid >> 3, schunk = tid & 7;   // staging: 512 thr = 64 rows x 8 chunks
    const short* kbase = Kb + (size_t)b * NLK * NAD + h * 64 + schunk * 8;
    const short* vbase = Vt + (size_t)(b * NH + h) * 64 * NLK + schunk * 8;

    // V key-interleave constants for this thread's key group (keys schunk*8..+7):
    // k = t*32 + h16*16 + q*4 + j  ->  n = t*32 + q*8 + h16*4 + j.
    const int vt_ = schunk >> 2, vh_ = (schunk >> 1) & 1, vq0 = (schunk * 2) & 3;
    const int vcl = vt_ * 4 + vq0;        // 16B chunk for j=0..3 (even)
    const int voff = vh_ * 4;             // element offset within chunk

    // prologue: tile 0 into regs (one 16B chunk of K and of V per thread)
    bf16x8 kv = *(const bf16x8*)(kbase + (size_t)srow * NAD);
    bf16x8 vv = *(const bf16x8*)(vbase + (size_t)srow * NLK);

    for (int kt = 0; kt < NLK / 64; ++kt) {
        short* Kw = &Ks[kt & 1][0];
        short* Vw = &Vs[kt & 1][0];
        {
            const int c = (schunk ^ (srow & 7)) * 8;
            *(bf16x8*)&Kw[srow * 64 + c] = kv;
            // V: interleaved-key layout, two 8B writes (chunks vcl, vcl+1)
            const sh4 lo = { vv[0], vv[1], vv[2], vv[3] };
            const sh4 hi = { vv[4], vv[5], vv[6], vv[7] };
            *(sh4*)&Vw[srow * 64 + ((vcl ^ (srow & 7)) * 8 + voff)] = lo;
            *(sh4*)&Vw[srow * 64 + (((vcl + 1) ^ (srow & 7)) * 8 + voff)] = hi;
        }

        // prefetch next tile (global loads stay in flight across the barrier)
        const int nk = (kt + 1) & (NLK / 64 - 1);
        kv = *(const bf16x8*)(kbase + (size_t)(nk * 64 + srow) * NAD);
        vv = *(const bf16x8*)(vbase + (size_t)srow * NLK + nk * 64);

        SYNC_LDS;   // lgkmcnt(0) + s_barrier: writes visible, vmcnt untouched

        // ---- K A-fragments (shared across both mtq)
        bf16x8 kf[2][4];
        #pragma unroll
        for (int kk = 0; kk < 2; ++kk)
            #pragma unroll
            for (int nt = 0; nt < 4; ++nt) {
                const int key = nt * 16 + col;
                kf[kk][nt] = *(const bf16x8*)&Kw[key * 64 + (((kk * 4 + quad) ^ (key & 7)) * 8)];
            }

        // ---- per q-block: S^T, exp2, perm-pack to PV B-frags, l via ones-MFMA
        int pk[2][2][4];    // [mtq][t][dword]
        #pragma unroll
        for (int mt = 0; mt < 2; ++mt) {
            f32x4 st[4];
            #pragma unroll
            for (int nt = 0; nt < 4; ++nt) st[nt] = zero;
            __builtin_amdgcn_s_setprio(1);
            #pragma unroll
            for (int kk = 0; kk < 2; ++kk)
                #pragma unroll
                for (int nt = 0; nt < 4; ++nt)
                    st[nt] = __builtin_amdgcn_mfma_f32_16x16x32_bf16(kf[kk][nt], aq[mt][kk], st[nt], 0, 0, 0);
            __builtin_amdgcn_s_setprio(0);
            #pragma unroll
            for (int nt = 0; nt < 4; ++nt) {
                const unsigned u0 = __builtin_bit_cast(unsigned, __builtin_amdgcn_exp2f(st[nt][0]));
                const unsigned u1 = __builtin_bit_cast(unsigned, __builtin_amdgcn_exp2f(st[nt][1]));
                const unsigned u2 = __builtin_bit_cast(unsigned, __builtin_amdgcn_exp2f(st[nt][2]));
                const unsigned u3 = __builtin_bit_cast(unsigned, __builtin_amdgcn_exp2f(st[nt][3]));
                const int t = nt >> 1, odd = (nt & 1) * 2;
                pk[mt][t][odd + 0] = (int)__builtin_amdgcn_perm(u1, u0, 0x07060302u);
                pk[mt][t][odd + 1] = (int)__builtin_amdgcn_perm(u3, u2, 0x07060302u);
            }
            __builtin_amdgcn_s_setprio(1);
            #pragma unroll
            for (int t = 0; t < 2; ++t) {
                const bf16x8 pb = __builtin_bit_cast(bf16x8,
                    i32x4{pk[mt][t][0], pk[mt][t][1], pk[mt][t][2], pk[mt][t][3]});
                Ol[mt] = __builtin_amdgcn_mfma_f32_16x16x32_bf16(vones, pb, Ol[mt], 0, 0, 0);
            }
            __builtin_amdgcn_s_setprio(0);
        }

        // ---- O^T += V^T P^T  (interleaved-key Vs: ONE b128 per fragment)
        #pragma unroll
        for (int t = 0; t < 2; ++t)
            #pragma unroll
            for (int db = 0; db < 4; ++db) {
                const int row = db * 16 + col;   // d index
                const bf16x8 va = *(const bf16x8*)&Vw[row * 64 + (((t * 4 + quad) ^ (row & 7)) * 8)];
                __builtin_amdgcn_s_setprio(1);
                #pragma unroll
                for (int mt = 0; mt < 2; ++mt) {
                    const bf16x8 pb = __builtin_bit_cast(bf16x8,
                        i32x4{pk[mt][t][0], pk[mt][t][1], pk[mt][t][2], pk[mt][t][3]});
                    O[db][mt] = __builtin_amdgcn_mfma_f32_16x16x32_bf16(va, pb, O[db][mt], 0, 0, 0);
                }
                __builtin_amdgcn_s_setprio(0);
            }
    }

    // ---- epilogue: l already reduced (every lane holds it); packed b64 stores
    #pragma unroll
    for (int mt = 0; mt < 2; ++mt) {
        const float linv = 1.0f / Ol[mt][0];
        #pragma unroll
        for (int db = 0; db < 4; ++db) {
            sh4 o4;
            #pragma unroll
            for (int r = 0; r < 4; ++r)
                o4[r] = f2bf(O[db][mt][r] * linv);
            short* cp = ctx + (size_t)(b * NLQ + q0 + mt * 16 + col) * NAD
                      + h * 64 + db * 16 + quad * 4;
            *(sh4*)cp = o4;
        }
    }
}

extern "C" void kernel_launch(void* const* d_in, const int* in_sizes, int n_in,
                              void* d_out, int out_size, void* d_ws, size_t ws_size,
                              hipStream_t stream)
{
    (void)in_sizes; (void)n_in; (void)out_size; (void)ws_size;
    const float* x  = (const float*)d_in[0];
    const float* e  = (const float*)d_in[1];
    const float* Wq = (const float*)d_in[2];
    const float* bq = (const float*)d_in[3];
    const float* Wk = (const float*)d_in[4];
    const float* bk = (const float*)d_in[5];
    const float* Wv = (const float*)d_in[6];
    const float* bv = (const float*)d_in[7];
    const float* Wo = (const float*)d_in[8];
    const float* bo = (const float*)d_in[9];
    float* out = (float*)d_out;

    const size_t MQ = (size_t)NB * NLQ;          // 8192
    short* wsp = (short*)d_ws;
    short* Xb  = wsp;
    short* Eb  = Xb  + MQ * NDIM;
    short* Wqt = Eb  + MQ * NDIM;
    short* Wkt = Wqt + (size_t)NDIM * NAD;
    short* Wvt = Wkt + (size_t)NDIM * NAD;
    short* Wot = Wvt + (size_t)NDIM * NAD;
    short* Qb  = Wot + (size_t)NDIM * NAD;
    short* Kf  = Qb  + MQ * NAD;
    short* Vtb = Kf  + MQ * NAD;
    short* Cx  = Vtb + MQ * NAD;

    cvt2<<<dim3(8192, 2), 256, 0, stream>>>(x, e, Xb, Eb);
    wtrans4<<<dim3(32, 32, 4), 256, 0, stream>>>(Wq, Wk, Wv, Wo, Wqt, Wkt, Wvt, Wot);

    gemm_qkv<<<dim3(64, 8, 3), 256, 0, stream>>>(Xb, Eb, Wqt, Wkt, Wvt,
                                                 bq, bk, bv, Qb, Kf, Vtb);

    attn_fused13<<<dim3(NB * NH * (NLQ / 256)), 512, 0, stream>>>(Qb, Kf, Vtb, Cx);

    gemm_out<<<dim3(64, 8), 256, 0, stream>>>(Cx, Wot, bo, out);
}

// Round 9
// 285.145 us; speedup vs baseline: 1.0548x; 1.0548x over previous
//
#include <hip/hip_runtime.h>
#include <cstdint>
#include <cstddef>

#define NB   4
#define NLQ  2048
#define NLK  2048
#define NDIM 1024
#define NH   16
#define ND   64
#define NAD  1024

typedef __attribute__((ext_vector_type(8))) short bf16x8;
typedef __attribute__((ext_vector_type(4))) short sh4;
typedef __attribute__((ext_vector_type(4))) float f32x4;
typedef __attribute__((ext_vector_type(4))) int   i32x4;

static __device__ __forceinline__ short f2bf(float f) {
    unsigned u = __builtin_bit_cast(unsigned, f);
    u += 0x7fffu + ((u >> 16) & 1u);     // round-to-nearest-even
    return (short)(u >> 16);
}

// async global->LDS, 16B per lane; LDS dest lane-contiguous (global side may be swizzled)
#define GLL16(GP, LP) __builtin_amdgcn_global_load_lds( \
    (const __attribute__((address_space(1))) void*)(GP), \
    (__attribute__((address_space(3))) void*)(LP), 16, 0, 0)

// LDS-producer barrier WITHOUT the vmcnt drain of __syncthreads():
// drains only lgkmcnt (ds_writes visible), leaves global prefetch in flight.
#define SYNC_LDS do { \
    __builtin_amdgcn_sched_barrier(0); \
    asm volatile("s_waitcnt lgkmcnt(0)" ::: "memory"); \
    __builtin_amdgcn_s_barrier(); \
    asm volatile("" ::: "memory"); \
    __builtin_amdgcn_sched_barrier(0); } while (0)

// ---------------- merged preprocessing: cvt (x,e fp32->bf16) + 4x W transpose ----------------
// Blocks [0,16384): fp32->bf16 conversion (8192 for x, 8192 for e).
// Blocks [16384,20480): W[1024][1024] fp32 -> Wt[n][k] bf16 (1024 blocks per W).
// One launch instead of two: removes one inter-dispatch gap; the BW-bound cvt
// blocks and LDS-bound transpose blocks co-fill the machine.
__global__ void prep(const float* __restrict__ x, const float* __restrict__ e,
                     short* __restrict__ xo, short* __restrict__ eo,
                     const float* __restrict__ W0, const float* __restrict__ W1,
                     const float* __restrict__ W2, const float* __restrict__ W3,
                     short* __restrict__ T0, short* __restrict__ T1,
                     short* __restrict__ T2, short* __restrict__ T3) {
    __shared__ float t[32][33];
    const int id = blockIdx.x;
    if (id < 16384) {
        const float* in = (id >= 8192) ? e : x;
        short* out = (id >= 8192) ? eo : xo;
        const int i = ((id & 8191) * 256 + threadIdx.x) * 4;
        const float4 v = *(const float4*)(in + i);
        sh4 o;
        o.x = f2bf(v.x); o.y = f2bf(v.y); o.z = f2bf(v.z); o.w = f2bf(v.w);
        *(sh4*)(out + i) = o;
    } else {
        const int w = id - 16384;          // 0..4095
        const int z = w >> 10;
        const int rem = w & 1023;
        const float* W = (z == 0) ? W0 : (z == 1) ? W1 : (z == 2) ? W2 : W3;
        short* Wt = (z == 0) ? T0 : (z == 1) ? T1 : (z == 2) ? T2 : T3;
        const int bx = (rem & 31) * 32;    // k block
        const int by = (rem >> 5) * 32;    // n block
        const int tx = threadIdx.x & 31, ty = threadIdx.x >> 5;
        #pragma unroll
        for (int i = 0; i < 32; i += 8)
            t[ty + i][tx] = W[(size_t)(bx + ty + i) * 1024 + by + tx];
        __syncthreads();
        #pragma unroll
        for (int i = 0; i < 32; i += 8)
            Wt[(size_t)(by + ty + i) * 1024 + bx + tx] = f2bf(t[tx][ty + i]);
    }
}

// XCD L2-tiling remap for a 64x8 (x,y) block plane (512 blocks, 512%8==0 ->
// bijective). Dispatch order round-robins XCDs by linear id; give XCD k an
// 8x8 (x',y') super-tile: 8 A-panels + 8 B-panels = 2+2 MB = fits 4 MB L2.
static __device__ __forceinline__ void xcd_tile_remap(int f, int& bx, int& by) {
    bx = ((f & 7) << 3) | ((f >> 3) & 7);   // x' = 8*xcd + slot%8
    by = f >> 6;                            // y' = slot/8
}

// =====================================================================
// BK=64 GEMM body: C[M,1024] = A[M,1024] @ Wt[1024,1024]^T.
// (128x128 tile, 4 waves, 2-barrier loop; 256x256 deep-pipeline port
// measured WORSE here — retained. ~825 TF at K=1024 = this structure's
// ceiling per the m97-family data.)
// LDS rows are 64 shorts (128 B) -> XOR-swizzle 16B chunks applied on the
// GLOBAL address (global_load_lds needs lane-contiguous LDS dest); frag
// reads apply the matching XOR -> conflict-free b128.
// =====================================================================

// ---------------- fused Q/K/V projection GEMMs (one launch, grid.z selects) ----------------
__global__ __launch_bounds__(256) void gemm_qkv(const short* __restrict__ Xb,
                                                const short* __restrict__ Eb,
                                                const short* __restrict__ Wqt,
                                                const short* __restrict__ Wkt,
                                                const short* __restrict__ Wvt,
                                                const float* __restrict__ bq,
                                                const float* __restrict__ bk,
                                                const float* __restrict__ bv,
                                                short* __restrict__ Qb,
                                                short* __restrict__ Kf,
                                                short* __restrict__ Vtb)
{
    const int N = 1024, K = 1024;
    __shared__ __align__(16) short As[128 * 64];
    __shared__ __align__(16) short Bs[128 * 64];
    const int z = blockIdx.z;
    const short* A    = (z == 0) ? Xb : Eb;
    const short* Wt   = (z == 0) ? Wqt : (z == 1) ? Wkt : Wvt;
    const float* bias = (z == 0) ? bq : (z == 1) ? bk : bv;
    const float scale = (z == 0) ? 0.18033688011112042f : 1.0f;   // SCALE * LOG2E

    const int tid = threadIdx.x, wave = tid >> 6, lane = tid & 63;
    const int quad = lane >> 4, col = lane & 15;
    int bx, by;
    xcd_tile_remap(blockIdx.x + (blockIdx.y << 6), bx, by);
    const int m0 = bx * 128, n0 = by * 128;
    const int wm = wave >> 1, wn = wave & 1;

    const f32x4 zero = {0.f, 0.f, 0.f, 0.f};
    f32x4 acc[4][4];
    #pragma unroll
    for (int i = 0; i < 4; ++i)
        #pragma unroll
        for (int j = 0; j < 4; ++j)
            acc[i][j] = zero;

    for (int kt = 0; kt < K / 64; ++kt) {
        __syncthreads();
        #pragma unroll
        for (int i = 0; i < 4; ++i) {
            const int f = (i * 4 + wave) * 512 + lane * 8;   // lane-contiguous LDS offset
            const int row = f >> 6, ch = (f >> 3) & 7;
            const int gcol = kt * 64 + ((ch ^ (row & 7)) * 8);  // global-side swizzle
            GLL16(A  + (size_t)(m0 + row) * K + gcol, &As[f]);
            GLL16(Wt + (size_t)(n0 + row) * K + gcol, &Bs[f]);
        }
        __syncthreads();
        #pragma unroll
        for (int kk = 0; kk < 2; ++kk) {
            bf16x8 af[4], bfr[4];
            #pragma unroll
            for (int mt = 0; mt < 4; ++mt) {
                const int r = wm * 64 + mt * 16 + col;
                af[mt] = *(const bf16x8*)&As[r * 64 + (((kk * 4 + quad) ^ (r & 7)) * 8)];
            }
            #pragma unroll
            for (int nt = 0; nt < 4; ++nt) {
                const int r = wn * 64 + nt * 16 + col;
                bfr[nt] = *(const bf16x8*)&Bs[r * 64 + (((kk * 4 + quad) ^ (r & 7)) * 8)];
            }
            #pragma unroll
            for (int mt = 0; mt < 4; ++mt)
                #pragma unroll
                for (int nt = 0; nt < 4; ++nt)
                    acc[mt][nt] = __builtin_amdgcn_mfma_f32_16x16x32_bf16(af[mt], bfr[nt], acc[mt][nt], 0, 0, 0);
        }
    }

    if (z < 2) {
        short* outp = (z == 0) ? Qb : Kf;
        #pragma unroll
        for (int mt = 0; mt < 4; ++mt)
            #pragma unroll
            for (int nt = 0; nt < 4; ++nt) {
                const int n = n0 + wn * 64 + nt * 16 + col;
                const float bv_ = bias[n];
                #pragma unroll
                for (int r = 0; r < 4; ++r) {
                    const int m = m0 + wm * 64 + mt * 16 + quad * 4 + r;
                    outp[(size_t)m * N + n] = f2bf((acc[mt][nt][r] + bv_) * scale);
                }
            }
    } else {
        // V -> Vt[b,h,d,LK], packed 8B stores along s (r=0..3 contiguous in m)
        #pragma unroll
        for (int mt = 0; mt < 4; ++mt)
            #pragma unroll
            for (int nt = 0; nt < 4; ++nt) {
                const int n = n0 + wn * 64 + nt * 16 + col;
                const int hh = n >> 6, d = n & 63;
                const float bv_ = bias[n];
                const int mb = m0 + wm * 64 + mt * 16 + quad * 4;
                const int bb = mb >> 11, s = mb & 2047;
                sh4 o4;
                #pragma unroll
                for (int r = 0; r < 4; ++r)
                    o4[r] = f2bf(acc[mt][nt][r] + bv_);
                *(sh4*)&Vtb[((size_t)((bb * NH + hh) * 64 + d)) * NLK + s] = o4;
            }
    }
}

// ---------------- output projection GEMM (fp32 out), BK=64 ----------------
__global__ __launch_bounds__(256) void gemm_out(const short* __restrict__ A,
                                                const short* __restrict__ Wt,
                                                const float* __restrict__ bias,
                                                float* __restrict__ outp)
{
    const int N = 1024, K = 1024;
    __shared__ __align__(16) short As[128 * 64];
    __shared__ __align__(16) short Bs[128 * 64];
    const int tid = threadIdx.x, wave = tid >> 6, lane = tid & 63;
    const int quad = lane >> 4, col = lane & 15;
    int bx, by;
    xcd_tile_remap(blockIdx.x + (blockIdx.y << 6), bx, by);
    const int m0 = bx * 128, n0 = by * 128;
    const int wm = wave >> 1, wn = wave & 1;

    const f32x4 zero = {0.f, 0.f, 0.f, 0.f};
    f32x4 acc[4][4];
    #pragma unroll
    for (int i = 0; i < 4; ++i)
        #pragma unroll
        for (int j = 0; j < 4; ++j)
            acc[i][j] = zero;

    for (int kt = 0; kt < K / 64; ++kt) {
        __syncthreads();
        #pragma unroll
        for (int i = 0; i < 4; ++i) {
            const int f = (i * 4 + wave) * 512 + lane * 8;
            const int row = f >> 6, ch = (f >> 3) & 7;
            const int gcol = kt * 64 + ((ch ^ (row & 7)) * 8);
            GLL16(A  + (size_t)(m0 + row) * K + gcol, &As[f]);
            GLL16(Wt + (size_t)(n0 + row) * K + gcol, &Bs[f]);
        }
        __syncthreads();
        #pragma unroll
        for (int kk = 0; kk < 2; ++kk) {
            bf16x8 af[4], bfr[4];
            #pragma unroll
            for (int mt = 0; mt < 4; ++mt) {
                const int r = wm * 64 + mt * 16 + col;
                af[mt] = *(const bf16x8*)&As[r * 64 + (((kk * 4 + quad) ^ (r & 7)) * 8)];
            }
            #pragma unroll
            for (int nt = 0; nt < 4; ++nt) {
                const int r = wn * 64 + nt * 16 + col;
                bfr[nt] = *(const bf16x8*)&Bs[r * 64 + (((kk * 4 + quad) ^ (r & 7)) * 8)];
            }
            #pragma unroll
            for (int mt = 0; mt < 4; ++mt)
                #pragma unroll
                for (int nt = 0; nt < 4; ++nt)
                    acc[mt][nt] = __builtin_amdgcn_mfma_f32_16x16x32_bf16(af[mt], bfr[nt], acc[mt][nt], 0, 0, 0);
        }
    }

    #pragma unroll
    for (int mt = 0; mt < 4; ++mt)
        #pragma unroll
        for (int nt = 0; nt < 4; ++nt) {
            const int n = n0 + wn * 64 + nt * 16 + col;
            const float bv_ = bias[n];
            #pragma unroll
            for (int r = 0; r < 4; ++r) {
                const int m = m0 + wm * 64 + mt * 16 + quad * 4 + r;
                outp[(size_t)m * N + n] = acc[mt][nt][r] + bv_;
            }
        }
}

// ---------------- fused flash attention, v12 (best-known family) ----------------
// Structure log: v8/v13 wave-scaling NULL/negative (waves are barrier-phase-
// locked per tile, so occupancy does not overlap the MFMA and VALU pipes);
// v10/v11 intra-wave pipelining spilled/regressed; KVBLK=128 rejected on
// VGPR arithmetic (~290 live). v12 = v9 schedule + interleaved-key Vs:
// key k=(t,h16,q,j) stored at n=t*32+q*8+h16*4+j so each lane's 8 PV keys
// are one contiguous 16B chunk -> PV is ONE ds_read_b128 per fragment.
// Bank conflicts measured 0; WRITE_SIZE clean at 16.4 MB.
__global__ __launch_bounds__(256, 2) void attn_fused12(const short* __restrict__ Q,
                                                       const short* __restrict__ Kb,
                                                       const short* __restrict__ Vt,
                                                       short* __restrict__ ctx)
{
    __shared__ __align__(16) short Ks[2][64 * 64];   // [buf][key][dim], 16B-chunk XOR swizzle
    __shared__ __align__(16) short Vs[2][64 * 64];   // [buf][d][key-interleaved], XOR swizzle
    const int tid = threadIdx.x, wave = tid >> 6, lane = tid & 63;
    const int quad = lane >> 4, col = lane & 15;

    // XCD-grouping decode (bijective on [0,512)): physical p -> xcd = p%8.
    // group g=(b,h) gets xcd = g%8; its 8 q-tile members are p = g%8 + 8*(qt*8 + g/8).
    const int p = blockIdx.x;
    const int g = ((p >> 3) & 7) * 8 + (p & 7);   // (b,h) group 0..63
    const int qt = p >> 6;                         // q-tile member 0..7
    const int h = g & 15, b = g >> 4;
    const int q0 = qt * 256 + wave * 64;

    // Q B-fragments for the wave's 64 q-rows
    bf16x8 aq[4][2];
    #pragma unroll
    for (int mt = 0; mt < 4; ++mt) {
        const short* qp = Q + (size_t)(b * NLQ + q0 + mt * 16 + col) * NAD + h * 64 + quad * 8;
        aq[mt][0] = *(const bf16x8*)qp;
        aq[mt][1] = *(const bf16x8*)(qp + 32);
    }

    bf16x8 vones;
    #pragma unroll
    for (int j = 0; j < 8; ++j) vones[j] = (short)0x3F80;   // bf16 1.0

    const f32x4 zero = {0.f, 0.f, 0.f, 0.f};
    f32x4 O[4][4];          // [dblk][mtq], O^T C-layout
    f32x4 Ol[4];            // l accumulator (ones x P^T): all rows identical
    #pragma unroll
    for (int mt = 0; mt < 4; ++mt) {
        Ol[mt] = zero;
        #pragma unroll
        for (int db = 0; db < 4; ++db) O[db][mt] = zero;
    }

    const int srow = tid >> 3, schunk = tid & 7;   // staging: 8 lanes/row, 32 rows/round
    const short* kbase = Kb + (size_t)b * NLK * NAD + h * 64 + schunk * 8;
    const short* vbase = Vt + (size_t)(b * NH + h) * 64 * NLK + schunk * 8;

    // V key-interleave constants for this thread's key group (keys schunk*8..+7):
    // k = t*32 + h16*16 + q*4 + j  ->  n = t*32 + q*8 + h16*4 + j.
    const int vt_ = schunk >> 2, vh_ = (schunk >> 1) & 1, vq0 = (schunk * 2) & 3;
    const int vcl = vt_ * 4 + vq0;        // 16B chunk for j=0..3 (even)
    const int voff = vh_ * 4;             // element offset within chunk

    // prologue: tile 0 into regs
    bf16x8 kv[2], vv[2];
    #pragma unroll
    for (int i = 0; i < 2; ++i) {
        const int row = i * 32 + srow;
        kv[i] = *(const bf16x8*)(kbase + (size_t)row * NAD);
        vv[i] = *(const bf16x8*)(vbase + (size_t)row * NLK);
    }

    for (int kt = 0; kt < NLK / 64; ++kt) {
        short* Kw = &Ks[kt & 1][0];
        short* Vw = &Vs[kt & 1][0];
        #pragma unroll
        for (int i = 0; i < 2; ++i) {
            const int row = i * 32 + srow;
            const int c = (schunk ^ (row & 7)) * 8;
            *(bf16x8*)&Kw[row * 64 + c] = kv[i];
            // V: interleaved-key layout, two 8B writes (chunks vcl, vcl+1)
            const sh4 lo = { vv[i][0], vv[i][1], vv[i][2], vv[i][3] };
            const sh4 hi = { vv[i][4], vv[i][5], vv[i][6], vv[i][7] };
            *(sh4*)&Vw[row * 64 + ((vcl ^ (row & 7)) * 8 + voff)] = lo;
            *(sh4*)&Vw[row * 64 + (((vcl + 1) ^ (row & 7)) * 8 + voff)] = hi;
        }

        // prefetch next tile (global loads stay in flight across the barrier)
        const int nk = (kt + 1) & (NLK / 64 - 1);
        #pragma unroll
        for (int i = 0; i < 2; ++i) {
            const int row = i * 32 + srow;
            kv[i] = *(const bf16x8*)(kbase + (size_t)(nk * 64 + row) * NAD);
            vv[i] = *(const bf16x8*)(vbase + (size_t)row * NLK + nk * 64);
        }

        SYNC_LDS;   // lgkmcnt(0) + s_barrier: writes visible, vmcnt untouched

        // ---- K A-fragments (shared across all mtq)
        bf16x8 kf[2][4];
        #pragma unroll
        for (int kk = 0; kk < 2; ++kk)
            #pragma unroll
            for (int nt = 0; nt < 4; ++nt) {
                const int key = nt * 16 + col;
                kf[kk][nt] = *(const bf16x8*)&Kw[key * 64 + (((kk * 4 + quad) ^ (key & 7)) * 8)];
            }

        // ---- per q-block: S^T, exp2, perm-pack to PV B-frags, l via ones-MFMA
        int pk[4][2][4];    // [mtq][t][dword]
        #pragma unroll
        for (int mt = 0; mt < 4; ++mt) {
            f32x4 st[4];
            #pragma unroll
            for (int nt = 0; nt < 4; ++nt) st[nt] = zero;
            __builtin_amdgcn_s_setprio(1);
            #pragma unroll
            for (int kk = 0; kk < 2; ++kk)
                #pragma unroll
                for (int nt = 0; nt < 4; ++nt)
                    st[nt] = __builtin_amdgcn_mfma_f32_16x16x32_bf16(kf[kk][nt], aq[mt][kk], st[nt], 0, 0, 0);
            __builtin_amdgcn_s_setprio(0);
            #pragma unroll
            for (int nt = 0; nt < 4; ++nt) {
                const unsigned u0 = __builtin_bit_cast(unsigned, __builtin_amdgcn_exp2f(st[nt][0]));
                const unsigned u1 = __builtin_bit_cast(unsigned, __builtin_amdgcn_exp2f(st[nt][1]));
                const unsigned u2 = __builtin_bit_cast(unsigned, __builtin_amdgcn_exp2f(st[nt][2]));
                const unsigned u3 = __builtin_bit_cast(unsigned, __builtin_amdgcn_exp2f(st[nt][3]));
                const int t = nt >> 1, odd = (nt & 1) * 2;
                pk[mt][t][odd + 0] = (int)__builtin_amdgcn_perm(u1, u0, 0x07060302u);
                pk[mt][t][odd + 1] = (int)__builtin_amdgcn_perm(u3, u2, 0x07060302u);
            }
            __builtin_amdgcn_s_setprio(1);
            #pragma unroll
            for (int t = 0; t < 2; ++t) {
                const bf16x8 pb = __builtin_bit_cast(bf16x8,
                    i32x4{pk[mt][t][0], pk[mt][t][1], pk[mt][t][2], pk[mt][t][3]});
                Ol[mt] = __builtin_amdgcn_mfma_f32_16x16x32_bf16(vones, pb, Ol[mt], 0, 0, 0);
            }
            __builtin_amdgcn_s_setprio(0);
        }

        // ---- O^T += V^T P^T  (interleaved-key Vs: ONE b128 per fragment)
        #pragma unroll
        for (int t = 0; t < 2; ++t)
            #pragma unroll
            for (int db = 0; db < 4; ++db) {
                const int row = db * 16 + col;   // d index
                const bf16x8 va = *(const bf16x8*)&Vw[row * 64 + (((t * 4 + quad) ^ (row & 7)) * 8)];
                __builtin_amdgcn_s_setprio(1);
                #pragma unroll
                for (int mt = 0; mt < 4; ++mt) {
                    const bf16x8 pb = __builtin_bit_cast(bf16x8,
                        i32x4{pk[mt][t][0], pk[mt][t][1], pk[mt][t][2], pk[mt][t][3]});
                    O[db][mt] = __builtin_amdgcn_mfma_f32_16x16x32_bf16(va, pb, O[db][mt], 0, 0, 0);
                }
                __builtin_amdgcn_s_setprio(0);
            }
    }

    // ---- epilogue: l already reduced (every lane holds it); packed b64 stores
    #pragma unroll
    for (int mt = 0; mt < 4; ++mt) {
        const float linv = 1.0f / Ol[mt][0];
        #pragma unroll
        for (int db = 0; db < 4; ++db) {
            sh4 o4;
            #pragma unroll
            for (int r = 0; r < 4; ++r)
                o4[r] = f2bf(O[db][mt][r] * linv);
            short* cp = ctx + (size_t)(b * NLQ + q0 + mt * 16 + col) * NAD
                      + h * 64 + db * 16 + quad * 4;
            *(sh4*)cp = o4;
        }
    }
}

extern "C" void kernel_launch(void* const* d_in, const int* in_sizes, int n_in,
                              void* d_out, int out_size, void* d_ws, size_t ws_size,
                              hipStream_t stream)
{
    (void)in_sizes; (void)n_in; (void)out_size; (void)ws_size;
    const float* x  = (const float*)d_in[0];
    const float* e  = (const float*)d_in[1];
    const float* Wq = (const float*)d_in[2];
    const float* bq = (const float*)d_in[3];
    const float* Wk = (const float*)d_in[4];
    const float* bk = (const float*)d_in[5];
    const float* Wv = (const float*)d_in[6];
    const float* bv = (const float*)d_in[7];
    const float* Wo = (const float*)d_in[8];
    const float* bo = (const float*)d_in[9];
    float* out = (float*)d_out;

    const size_t MQ = (size_t)NB * NLQ;          // 8192
    short* wsp = (short*)d_ws;
    short* Xb  = wsp;
    short* Eb  = Xb  + MQ * NDIM;
    short* Wqt = Eb  + MQ * NDIM;
    short* Wkt = Wqt + (size_t)NDIM * NAD;
    short* Wvt = Wkt + (size_t)NDIM * NAD;
    short* Wot = Wvt + (size_t)NDIM * NAD;
    short* Qb  = Wot + (size_t)NDIM * NAD;
    short* Kf  = Qb  + MQ * NAD;
    short* Vtb = Kf  + MQ * NAD;
    short* Cx  = Vtb + MQ * NAD;

    prep<<<dim3(20480), 256, 0, stream>>>(x, e, Xb, Eb,
                                          Wq, Wk, Wv, Wo, Wqt, Wkt, Wvt, Wot);

    gemm_qkv<<<dim3(64, 8, 3), 256, 0, stream>>>(Xb, Eb, Wqt, Wkt, Wvt,
                                                 bq, bk, bv, Qb, Kf, Vtb);

    attn_fused12<<<dim3(NB * NH * (NLQ / 256)), 256, 0, stream>>>(Qb, Kf, Vtb, Cx);

    gemm_out<<<dim3(64, 8), 256, 0, stream>>>(Cx, Wot, bo, out);
}